// Round 5
// baseline (1936.456 us; speedup 1.0000x reference)
//
#include <hip/hip_runtime.h>
#include <cstdint>

#define T_STEPS 128
#define BATCH 64
#define IDIM 2048
#define HDIM 512
#define G4 2048   // 4*H
#define NCLS 11

typedef __attribute__((ext_vector_type(8))) short bf16x8;
typedef __attribute__((ext_vector_type(4))) float f32x4;

__device__ __forceinline__ unsigned short f2bf(float f) {
    unsigned int u = __builtin_bit_cast(unsigned int, f);
    unsigned int r = u + 0x7FFFu + ((u >> 16) & 1u);   // RNE
    return (unsigned short)(r >> 16);
}
__device__ __forceinline__ float bf2f(unsigned short b) {
    unsigned int u = ((unsigned int)b) << 16;
    return __builtin_bit_cast(float, u);
}
__device__ __forceinline__ float sigm_fast(float x) {
    return 1.f / (1.f + __expf(-x));
}
__device__ __forceinline__ float tanh_fast(float x) {
    float e = __expf(2.f * x);        // inf-safe: x>>0 -> 1, x<<0 -> -1
    return 1.f - 2.f / (e + 1.f);
}

#define FLAG_STRIDE 32   // ints: 128 B per WG flag line

// ---------------------------------------------------------------------------
// Prep: permute gate rows to interleaved order (n' = 4*j + gate), split
// weights into bf16 hi/lo, combine biases, pack h0 into h_pk buffer 0
// (u32 = hi | lo<<16, device-coherent), zero the barrier flags.
// orig_row(n') = (n'&3)*512 + (n'>>2)
// ---------------------------------------------------------------------------
__global__ void prep_kernel(const float* __restrict__ W_ih, const float* __restrict__ W_hh,
                            const float* __restrict__ b_ih, const float* __restrict__ b_hh,
                            const float* __restrict__ h0,
                            unsigned short* __restrict__ wih_hi, unsigned short* __restrict__ wih_lo,
                            unsigned short* __restrict__ whh_hi, unsigned short* __restrict__ whh_lo,
                            float* __restrict__ bc,
                            unsigned int* __restrict__ h_pk,
                            int* __restrict__ flags) {
    int idx = blockIdx.x * blockDim.x + threadIdx.x;
    int stride = gridDim.x * blockDim.x;
    for (int i = idx; i < 64 * FLAG_STRIDE; i += stride)
        __hip_atomic_store(flags + i, 0, __ATOMIC_RELAXED, __HIP_MEMORY_SCOPE_AGENT);
    for (int i = idx; i < G4 * IDIM; i += stride) {
        int np = i / IDIM, k = i - np * IDIM;
        int orig = (np & 3) * HDIM + (np >> 2);
        float f = W_ih[(size_t)orig * IDIM + k];
        unsigned short hi = f2bf(f);
        wih_hi[i] = hi;
        wih_lo[i] = f2bf(f - bf2f(hi));
    }
    for (int i = idx; i < G4 * HDIM; i += stride) {
        int np = i / HDIM, k = i - np * HDIM;
        int orig = (np & 3) * HDIM + (np >> 2);
        float f = W_hh[(size_t)orig * HDIM + k];
        unsigned short hi = f2bf(f);
        whh_hi[i] = hi;
        whh_lo[i] = f2bf(f - bf2f(hi));
    }
    for (int i = idx; i < G4; i += stride) {
        int orig = (i & 3) * HDIM + (i >> 2);
        bc[i] = b_ih[orig] + b_hh[orig];
    }
    for (int i = idx; i < BATCH * HDIM; i += stride) {
        float f = h0[i];
        unsigned short hi = f2bf(f);
        unsigned short lo = f2bf(f - bf2f(hi));
        __hip_atomic_store(h_pk + i, (unsigned)hi | ((unsigned)lo << 16),
                           __ATOMIC_RELAXED, __HIP_MEMORY_SCOPE_AGENT);
    }
}

// ---------------------------------------------------------------------------
// xg GEMM: xg[8192][2048] = x[8192][2048] @ Wih''^T + bc   (split-3 bf16 MFMA)
// 128x128 tile, BK=64, 256 threads (4 waves, each a 64x64 quadrant).
// ---------------------------------------------------------------------------
__global__ __launch_bounds__(256) void gemm_xg(const float* __restrict__ x,
        const unsigned short* __restrict__ wih_hi, const unsigned short* __restrict__ wih_lo,
        const float* __restrict__ bc, float* __restrict__ xg) {
    __shared__ unsigned short As_hi[128][64];
    __shared__ unsigned short As_lo[128][64];
    __shared__ unsigned short Bs_hi[128][64];
    __shared__ unsigned short Bs_lo[128][64];

    int tid = threadIdx.x;
    int w = tid >> 6, l = tid & 63;
    int lr = l & 15, lc = l >> 4;
    int bid = blockIdx.x;
    int mt = bid & 63, nt = bid >> 6;       // 64 M-tiles x 16 N-tiles
    int m0 = mt * 128, n0 = nt * 128;
    int mq = (w >> 1) * 64, nq = (w & 1) * 64;

    f32x4 acc[4][4] = {};

    for (int k0 = 0; k0 < IDIM; k0 += 64) {
        // stage A: f32 -> bf16 hi/lo
        #pragma unroll
        for (int i = 0; i < 8; ++i) {
            int p = i * 256 + tid;            // 0..2047 : 128 rows x 16 chunks
            int r = p >> 4, c4 = p & 15;
            const float4 v = *(const float4*)(x + (size_t)(m0 + r) * IDIM + k0 + c4 * 4);
            unsigned short h0_ = f2bf(v.x), h1_ = f2bf(v.y), h2_ = f2bf(v.z), h3_ = f2bf(v.w);
            unsigned short l0_ = f2bf(v.x - bf2f(h0_));
            unsigned short l1_ = f2bf(v.y - bf2f(h1_));
            unsigned short l2_ = f2bf(v.z - bf2f(h2_));
            unsigned short l3_ = f2bf(v.w - bf2f(h3_));
            uint2 hw, lw;
            hw.x = (unsigned)h0_ | ((unsigned)h1_ << 16);
            hw.y = (unsigned)h2_ | ((unsigned)h3_ << 16);
            lw.x = (unsigned)l0_ | ((unsigned)l1_ << 16);
            lw.y = (unsigned)l2_ | ((unsigned)l3_ << 16);
            *(uint2*)&As_hi[r][c4 * 4] = hw;
            *(uint2*)&As_lo[r][c4 * 4] = lw;
        }
        // stage B: bf16 copy (W'' is [n'][k], k contiguous)
        #pragma unroll
        for (int i = 0; i < 4; ++i) {
            int q = i * 256 + tid;            // 0..1023 : 128 rows x 8 chunks
            int n = q >> 3, c16 = q & 7;
            size_t goff = (size_t)(n0 + n) * IDIM + k0 + c16 * 8;
            *(uint4*)&Bs_hi[n][c16 * 8] = *(const uint4*)(wih_hi + goff);
            *(uint4*)&Bs_lo[n][c16 * 8] = *(const uint4*)(wih_lo + goff);
        }
        __syncthreads();

        #pragma unroll
        for (int ks = 0; ks < 2; ++ks) {
            bf16x8 ah[4], al[4], bh[4], bl[4];
            int col = ks * 32 + lc * 8;
            #pragma unroll
            for (int mb = 0; mb < 4; ++mb) {
                int row = mq + mb * 16 + lr;
                ah[mb] = *(const bf16x8*)&As_hi[row][col];
                al[mb] = *(const bf16x8*)&As_lo[row][col];
            }
            #pragma unroll
            for (int nb = 0; nb < 4; ++nb) {
                int row = nq + nb * 16 + lr;
                bh[nb] = *(const bf16x8*)&Bs_hi[row][col];
                bl[nb] = *(const bf16x8*)&Bs_lo[row][col];
            }
            #pragma unroll
            for (int mb = 0; mb < 4; ++mb)
                #pragma unroll
                for (int nb = 0; nb < 4; ++nb) {
                    acc[mb][nb] = __builtin_amdgcn_mfma_f32_16x16x32_bf16(ah[mb], bh[nb], acc[mb][nb], 0, 0, 0);
                    acc[mb][nb] = __builtin_amdgcn_mfma_f32_16x16x32_bf16(ah[mb], bl[nb], acc[mb][nb], 0, 0, 0);
                    acc[mb][nb] = __builtin_amdgcn_mfma_f32_16x16x32_bf16(al[mb], bh[nb], acc[mb][nb], 0, 0, 0);
                }
        }
        __syncthreads();
    }

    // epilogue: + bias, store f32
    #pragma unroll
    for (int mb = 0; mb < 4; ++mb) {
        #pragma unroll
        for (int nb = 0; nb < 4; ++nb) {
            int col = n0 + nq + nb * 16 + lr;
            float bias = bc[col];
            #pragma unroll
            for (int r = 0; r < 4; ++r) {
                int row = m0 + mq + mb * 16 + lc * 4 + r;
                xg[(size_t)row * G4 + col] = acc[mb][nb][r] + bias;
            }
        }
    }
}

// ---------------------------------------------------------------------------
// Recurrence v2: 64 WGs x 256 thr. Key change vs R4: h-loads are no longer
// dependency-chained IC fragment gathers. Each wave STREAMS its own K-quarter
// of h (64 rows x 128 packed u32 = 32 KB) into LDS via batched coherent u64
// loads + XOR-swizzled ds_write_b128, then MFMA reads conflict-free LDS
// fragments. Per-wave producer barrier: wave w only needs the 16 WGs that
// produce hidden units [w*128,(w+1)*128), so it polls just those 16 flags.
// red[] aliases the first 8 KB of each wave's staging quarter (reads of the
// quarter all precede red writes; DS ops are wave-ordered). LDS total 128 KB.
// ---------------------------------------------------------------------------
__global__ __launch_bounds__(256, 1) void lstm_rec(
        const unsigned short* __restrict__ whh_hi, const unsigned short* __restrict__ whh_lo,
        const float* __restrict__ xg, const float* __restrict__ c0,
        const float* __restrict__ mask_h, const float* __restrict__ mask_c,
        unsigned int* __restrict__ h_pk,
        unsigned int* __restrict__ h_mean,
        const float* __restrict__ W_out, const float* __restrict__ b_out,
        float* __restrict__ out, int* __restrict__ flags) {
    __shared__ unsigned int hs[4][8192];    // 4 x 32 KB staging quarters (128 KB)

    int g = blockIdx.x, tid = threadIdx.x;
    int w = tid >> 6, l = tid & 63;
    int lr = l & 15, lc = l >> 4;
    unsigned int* hsw = hs[w];
    char* hsb = (char*)hsw;

    // B fragments (Whh'' slice), resident in registers for the whole loop
    bf16x8 bh[2][4], bl[2][4];
    #pragma unroll
    for (int nb = 0; nb < 2; ++nb)
        #pragma unroll
        for (int ks = 0; ks < 4; ++ks) {
            int n = g * 32 + nb * 16 + lr;
            int k = w * 128 + ks * 32 + lc * 8;
            bh[nb][ks] = *(const bf16x8*)(whh_hi + (size_t)n * HDIM + k);
            bl[nb][ks] = *(const bf16x8*)(whh_lo + (size_t)n * HDIM + k);
        }

    // two cells per thread
    int b0_ = tid >> 3, jl0 = tid & 7, jg0 = g * 8 + jl0;
    int b1_ = (tid + 256) >> 3, jl1 = tid & 7, jg1 = g * 8 + jl1;
    float c_0 = c0[b0_ * HDIM + jg0];
    float c_1 = c0[b1_ * HDIM + jg1];
    float ha0 = 0.f, ha1 = 0.f;

    // prefetch t=0 operands
    float4 xgv0 = *(const float4*)(xg + (size_t)(0 * BATCH + b0_) * G4 + g * 32 + jl0 * 4);
    float4 xgv1 = *(const float4*)(xg + (size_t)(0 * BATCH + b1_) * G4 + g * 32 + jl1 * 4);
    float mh0 = mask_h[(size_t)b0_ * HDIM + jg0], mc0 = mask_c[(size_t)b0_ * HDIM + jg0];
    float mh1 = mask_h[(size_t)b1_ * HDIM + jg1], mc1 = mask_c[(size_t)b1_ * HDIM + jg1];

    int myflag = (w * 16 + (l & 15)) * FLAG_STRIDE;   // this wave's 16 producers

    for (int t = 0; t < T_STEPS; ++t) {
        int cur = (t & 1) * (BATCH * HDIM);
        int nxt = ((t + 1) & 1) * (BATCH * HDIM);

        // (A) per-wave producer barrier: wait until the 16 WGs feeding this
        // wave's K-quarter have published h(t). t=0 is trivially satisfied.
        if (t > 0 && (l & 48) == 0) {   // lanes 0..15 poll (others converge)
            while (__hip_atomic_load(flags + myflag, __ATOMIC_RELAXED, __HIP_MEMORY_SCOPE_AGENT) < t)
                __builtin_amdgcn_s_sleep(1);
        }

        // (B) stream this wave's K-quarter into LDS. Lane l owns global row l.
        //     XOR swizzle on 16B units: unit u at row r lands at u^(r&7).
        {
            const unsigned long long* src =
                (const unsigned long long*)(h_pk + cur + l * HDIM + w * 128);
            char* dst = hsb + l * 512;
            int rs = l & 7;
            #pragma unroll
            for (int c = 0; c < 4; ++c) {                 // 4 chunks x 8 b128-units
                unsigned long long q[16];
                #pragma unroll
                for (int i = 0; i < 16; ++i)
                    q[i] = __hip_atomic_load(src + c * 16 + i, __ATOMIC_RELAXED, __HIP_MEMORY_SCOPE_AGENT);
                #pragma unroll
                for (int u = 0; u < 8; ++u) {
                    uint4 v;
                    v.x = (unsigned)q[2 * u];     v.y = (unsigned)(q[2 * u] >> 32);
                    v.z = (unsigned)q[2 * u + 1]; v.w = (unsigned)(q[2 * u + 1] >> 32);
                    *(uint4*)(dst + (((c * 8 + u) ^ rs) * 16)) = v;
                }
            }
        }

        // (C) MFMA from LDS (swizzled, ~conflict-free)
        f32x4 acc[4][2] = {};
        #pragma unroll
        for (int ks = 0; ks < 4; ++ks) {
            #pragma unroll
            for (int mb = 0; mb < 4; ++mb) {
                int row = mb * 16 + lr;
                int rs = row & 7;
                int u0 = ks * 8 + lc * 2;
                const uint4 d0 = *(const uint4*)(hsb + row * 512 + ((u0 ^ rs) * 16));
                const uint4 d1 = *(const uint4*)(hsb + row * 512 + (((u0 + 1) ^ rs) * 16));
                union { unsigned int d[4]; bf16x8 v; } ahu, alu;
                ahu.d[0] = __builtin_amdgcn_perm(d0.y, d0.x, 0x05040100u);
                alu.d[0] = __builtin_amdgcn_perm(d0.y, d0.x, 0x07060302u);
                ahu.d[1] = __builtin_amdgcn_perm(d0.w, d0.z, 0x05040100u);
                alu.d[1] = __builtin_amdgcn_perm(d0.w, d0.z, 0x07060302u);
                ahu.d[2] = __builtin_amdgcn_perm(d1.y, d1.x, 0x05040100u);
                alu.d[2] = __builtin_amdgcn_perm(d1.y, d1.x, 0x07060302u);
                ahu.d[3] = __builtin_amdgcn_perm(d1.w, d1.z, 0x05040100u);
                alu.d[3] = __builtin_amdgcn_perm(d1.w, d1.z, 0x07060302u);
                bf16x8 ah = ahu.v, al = alu.v;
                #pragma unroll
                for (int nb = 0; nb < 2; ++nb) {
                    acc[mb][nb] = __builtin_amdgcn_mfma_f32_16x16x32_bf16(ah, bh[nb][ks], acc[mb][nb], 0, 0, 0);
                    acc[mb][nb] = __builtin_amdgcn_mfma_f32_16x16x32_bf16(ah, bl[nb][ks], acc[mb][nb], 0, 0, 0);
                    acc[mb][nb] = __builtin_amdgcn_mfma_f32_16x16x32_bf16(al, bh[nb][ks], acc[mb][nb], 0, 0, 0);
                }
            }
        }

        // (D) red write: aliases first 8 KB of this wave's quarter (rows 0-15,
        // all already consumed above; DS ops are in-order within a wave)
        #pragma unroll
        for (int mb = 0; mb < 4; ++mb)
            #pragma unroll
            for (int nb = 0; nb < 2; ++nb)
                #pragma unroll
                for (int r = 0; r < 4; ++r)
                    ((float*)hsw)[(mb * 16 + lc * 4 + r) * 32 + nb * 16 + lr] = acc[mb][nb][r];
        __syncthreads();

        // (F) cell phase: 2 cells per thread; h store via returning exchange (IC)
        const float* red0 = (const float*)hs[0];
        const float* red1 = (const float*)hs[1];
        const float* red2 = (const float*)hs[2];
        const float* red3 = (const float*)hs[3];
        #pragma unroll
        for (int e = 0; e < 2; ++e) {
            int b  = e ? b1_ : b0_;
            int jl = e ? jl1 : jl0;
            int jg = e ? jg1 : jg0;
            float c_reg = e ? c_1 : c_0;
            int nb4 = b * 32 + jl * 4;
            float gi = red0[nb4 + 0] + red1[nb4 + 0] + red2[nb4 + 0] + red3[nb4 + 0];
            float gf = red0[nb4 + 1] + red1[nb4 + 1] + red2[nb4 + 1] + red3[nb4 + 1];
            float gg = red0[nb4 + 2] + red1[nb4 + 2] + red2[nb4 + 2] + red3[nb4 + 2];
            float go = red0[nb4 + 3] + red1[nb4 + 3] + red2[nb4 + 3] + red3[nb4 + 3];
            const float4 xgv = e ? xgv1 : xgv0;
            gi += xgv.x; gf += xgv.y; gg += xgv.z; go += xgv.w;
            float i_s = sigm_fast(gi);
            float f_s = sigm_fast(gf);
            float o_s = sigm_fast(go);
            float c_new = f_s * c_reg + i_s * tanh_fast(gg);
            float h_new = o_s * tanh_fast(c_new);
            h_new *= (e ? mh1 : mh0);
            c_new *= (e ? mc1 : mc0);
            if (e) { c_1 = c_new; ha1 += h_new; } else { c_0 = c_new; ha0 += h_new; }
            unsigned short hh = f2bf(h_new);
            unsigned short hl = f2bf(h_new - bf2f(hh));
            unsigned int pk = (unsigned)hh | ((unsigned)hl << 16);
            unsigned int old = __hip_atomic_exchange(h_pk + nxt + b * HDIM + jg, pk,
                                                     __ATOMIC_RELAXED, __HIP_MEMORY_SCOPE_AGENT);
            asm volatile("" :: "v"(old));   // returning form: vmcnt-ack == IC visibility
        }

        // prefetch next-step operands (latency hidden under next poll/stage)
        {
            int tp = (t + 1 < T_STEPS) ? t + 1 : T_STEPS - 1;
            xgv0 = *(const float4*)(xg + (size_t)(tp * BATCH + b0_) * G4 + g * 32 + jl0 * 4);
            xgv1 = *(const float4*)(xg + (size_t)(tp * BATCH + b1_) * G4 + g * 32 + jl1 * 4);
            size_t mi0 = (size_t)(tp * BATCH + b0_) * HDIM + jg0;
            size_t mi1 = (size_t)(tp * BATCH + b1_) * HDIM + jg1;
            mh0 = mask_h[mi0]; mc0 = mask_c[mi0];
            mh1 = mask_h[mi1]; mc1 = mask_c[mi1];
        }

        // (G) join: all waves' red reads done + all exchanges vmcnt-drained
        __syncthreads();
        // (H) publish
        if (tid == 0)
            __hip_atomic_store(flags + g * FLAG_STRIDE, t + 1, __ATOMIC_RELAXED, __HIP_MEMORY_SCOPE_AGENT);
    }

    // h_mean via returning exchange (device-coherent for cross-WG projection)
    {
        unsigned int m0v = __builtin_bit_cast(unsigned int, ha0 * (1.f / T_STEPS));
        unsigned int m1v = __builtin_bit_cast(unsigned int, ha1 * (1.f / T_STEPS));
        unsigned int o0 = __hip_atomic_exchange(h_mean + b0_ * HDIM + jg0, m0v,
                                                __ATOMIC_RELAXED, __HIP_MEMORY_SCOPE_AGENT);
        unsigned int o1 = __hip_atomic_exchange(h_mean + b1_ * HDIM + jg1, m1v,
                                                __ATOMIC_RELAXED, __HIP_MEMORY_SCOPE_AGENT);
        asm volatile("" :: "v"(o0), "v"(o1));
    }
    __syncthreads();
    if (tid == 0)
        __hip_atomic_store(flags + g * FLAG_STRIDE, T_STEPS + 1, __ATOMIC_RELAXED, __HIP_MEMORY_SCOPE_AGENT);
    if (tid < 64) {
        while (__hip_atomic_load(flags + tid * FLAG_STRIDE, __ATOMIC_RELAXED, __HIP_MEMORY_SCOPE_AGENT) < T_STEPS + 1)
            __builtin_amdgcn_s_sleep(1);
    }
    __syncthreads();

    // projection: WG g handles batch b = g -> out[g*11 + cl]
    {
        float part[NCLS];
        #pragma unroll
        for (int cl = 0; cl < NCLS; ++cl) part[cl] = 0.f;
        for (int j = tid; j < HDIM; j += 256) {
            unsigned int uv = __hip_atomic_load(h_mean + g * HDIM + j, __ATOMIC_RELAXED, __HIP_MEMORY_SCOPE_AGENT);
            float hv = __builtin_bit_cast(float, uv);
            #pragma unroll
            for (int cl = 0; cl < NCLS; ++cl)
                part[cl] += hv * W_out[cl * HDIM + j];
        }
        float* rbuf = (float*)hs;                 // staging LDS reused
        #pragma unroll
        for (int cl = 0; cl < NCLS; ++cl) rbuf[cl * 256 + tid] = part[cl];
        __syncthreads();
        if (tid < NCLS) {
            float s = b_out[tid];
            for (int i = 0; i < 256; ++i) s += rbuf[tid * 256 + i];
            out[g * NCLS + tid] = s;
        }
    }
}

// ---------------------------------------------------------------------------
extern "C" void kernel_launch(void* const* d_in, const int* in_sizes, int n_in,
                              void* d_out, int out_size, void* d_ws, size_t ws_size,
                              hipStream_t stream) {
    const float* x      = (const float*)d_in[0];
    const float* h0     = (const float*)d_in[1];
    const float* c0     = (const float*)d_in[2];
    const float* W_ih   = (const float*)d_in[3];
    const float* W_hh   = (const float*)d_in[4];
    const float* b_ih   = (const float*)d_in[5];
    const float* b_hh   = (const float*)d_in[6];
    const float* W_out  = (const float*)d_in[7];
    const float* b_out  = (const float*)d_in[8];
    const float* mask_h = (const float*)d_in[9];
    const float* mask_c = (const float*)d_in[10];
    float* out = (float*)d_out;

    char* ws = (char*)d_ws;
    float*          xg     = (float*)(ws + 0);               // 67,108,864 B
    unsigned short* wih_hi = (unsigned short*)(ws + 67108864);   // 8,388,608
    unsigned short* wih_lo = (unsigned short*)(ws + 75497472);   // 8,388,608
    unsigned short* whh_hi = (unsigned short*)(ws + 83886080);   // 2,097,152
    unsigned short* whh_lo = (unsigned short*)(ws + 85983232);   // 2,097,152
    float*          bc     = (float*)(ws + 88080384);            // 8,192
    unsigned int*   h_pk   = (unsigned int*)(ws + 88088576);     // 262,144 (2 bufs)
    unsigned int*   h_mean = (unsigned int*)(ws + 88350720);     // 131,072
    int*            flags  = (int*)(ws + 88481792);              // 8,192

    prep_kernel<<<8192, 256, 0, stream>>>(W_ih, W_hh, b_ih, b_hh, h0,
                                          wih_hi, wih_lo, whh_hi, whh_lo, bc, h_pk, flags);
    gemm_xg<<<1024, 256, 0, stream>>>(x, wih_hi, wih_lo, bc, xg);

    void* args[] = { &whh_hi, &whh_lo, &xg, &c0, &mask_h, &mask_c,
                     &h_pk, &h_mean, &W_out, &b_out, &out, &flags };
    hipLaunchCooperativeKernel((void*)lstm_rec, dim3(64), dim3(256), args, 0, stream);
}

// Round 6
// 1628.407 us; speedup vs baseline: 1.1892x; 1.1892x over previous
//
#include <hip/hip_runtime.h>
#include <cstdint>

#define T_STEPS 128
#define BATCH 64
#define IDIM 2048
#define HDIM 512
#define G4 2048   // 4*H
#define NCLS 11

typedef __attribute__((ext_vector_type(8))) short bf16x8;
typedef __attribute__((ext_vector_type(4))) float f32x4;

__device__ __forceinline__ unsigned short f2bf(float f) {
    unsigned int u = __builtin_bit_cast(unsigned int, f);
    unsigned int r = u + 0x7FFFu + ((u >> 16) & 1u);   // RNE
    return (unsigned short)(r >> 16);
}
__device__ __forceinline__ float bf2f(unsigned short b) {
    unsigned int u = ((unsigned int)b) << 16;
    return __builtin_bit_cast(float, u);
}
__device__ __forceinline__ float sigm_fast(float x) {
    return 1.f / (1.f + __expf(-x));
}
__device__ __forceinline__ float tanh_fast(float x) {
    float e = __expf(2.f * x);        // inf-safe: x>>0 -> 1, x<<0 -> -1
    return 1.f - 2.f / (e + 1.f);
}

// ---------------------------------------------------------------------------
// Prep: permute gate rows to interleaved order (n' = 4*j + gate), split
// weights into bf16 hi/lo, combine biases, pack h0 into h_pk buffer 0
// (u32 = hi | lo<<16), copy c0 to c_state, zero h_sum.
// orig_row(n') = (n'&3)*512 + (n'>>2)
// ---------------------------------------------------------------------------
__global__ void prep_kernel(const float* __restrict__ W_ih, const float* __restrict__ W_hh,
                            const float* __restrict__ b_ih, const float* __restrict__ b_hh,
                            const float* __restrict__ h0, const float* __restrict__ c0,
                            unsigned short* __restrict__ wih_hi, unsigned short* __restrict__ wih_lo,
                            unsigned short* __restrict__ whh_hi, unsigned short* __restrict__ whh_lo,
                            float* __restrict__ bc,
                            unsigned int* __restrict__ h_pk,
                            float* __restrict__ c_state, float* __restrict__ h_sum) {
    int idx = blockIdx.x * blockDim.x + threadIdx.x;
    int stride = gridDim.x * blockDim.x;
    for (int i = idx; i < G4 * IDIM; i += stride) {
        int np = i / IDIM, k = i - np * IDIM;
        int orig = (np & 3) * HDIM + (np >> 2);
        float f = W_ih[(size_t)orig * IDIM + k];
        unsigned short hi = f2bf(f);
        wih_hi[i] = hi;
        wih_lo[i] = f2bf(f - bf2f(hi));
    }
    for (int i = idx; i < G4 * HDIM; i += stride) {
        int np = i / HDIM, k = i - np * HDIM;
        int orig = (np & 3) * HDIM + (np >> 2);
        float f = W_hh[(size_t)orig * HDIM + k];
        unsigned short hi = f2bf(f);
        whh_hi[i] = hi;
        whh_lo[i] = f2bf(f - bf2f(hi));
    }
    for (int i = idx; i < G4; i += stride) {
        int orig = (i & 3) * HDIM + (i >> 2);
        bc[i] = b_ih[orig] + b_hh[orig];
    }
    for (int i = idx; i < BATCH * HDIM; i += stride) {
        float f = h0[i];
        unsigned short hi = f2bf(f);
        unsigned short lo = f2bf(f - bf2f(hi));
        h_pk[i] = (unsigned)hi | ((unsigned)lo << 16);   // buffer 0
        c_state[i] = c0[i];
        h_sum[i] = 0.f;
    }
}

// ---------------------------------------------------------------------------
// xg GEMM: xg[8192][2048] = x[8192][2048] @ Wih''^T + bc   (split-3 bf16 MFMA)
// 128x128 tile, BK=64, 256 threads (4 waves, each a 64x64 quadrant).
// ---------------------------------------------------------------------------
__global__ __launch_bounds__(256) void gemm_xg(const float* __restrict__ x,
        const unsigned short* __restrict__ wih_hi, const unsigned short* __restrict__ wih_lo,
        const float* __restrict__ bc, float* __restrict__ xg) {
    __shared__ unsigned short As_hi[128][64];
    __shared__ unsigned short As_lo[128][64];
    __shared__ unsigned short Bs_hi[128][64];
    __shared__ unsigned short Bs_lo[128][64];

    int tid = threadIdx.x;
    int w = tid >> 6, l = tid & 63;
    int lr = l & 15, lc = l >> 4;
    int bid = blockIdx.x;
    int mt = bid & 63, nt = bid >> 6;       // 64 M-tiles x 16 N-tiles
    int m0 = mt * 128, n0 = nt * 128;
    int mq = (w >> 1) * 64, nq = (w & 1) * 64;

    f32x4 acc[4][4] = {};

    for (int k0 = 0; k0 < IDIM; k0 += 64) {
        // stage A: f32 -> bf16 hi/lo
        #pragma unroll
        for (int i = 0; i < 8; ++i) {
            int p = i * 256 + tid;            // 0..2047 : 128 rows x 16 chunks
            int r = p >> 4, c4 = p & 15;
            const float4 v = *(const float4*)(x + (size_t)(m0 + r) * IDIM + k0 + c4 * 4);
            unsigned short h0_ = f2bf(v.x), h1_ = f2bf(v.y), h2_ = f2bf(v.z), h3_ = f2bf(v.w);
            unsigned short l0_ = f2bf(v.x - bf2f(h0_));
            unsigned short l1_ = f2bf(v.y - bf2f(h1_));
            unsigned short l2_ = f2bf(v.z - bf2f(h2_));
            unsigned short l3_ = f2bf(v.w - bf2f(h3_));
            uint2 hw, lw;
            hw.x = (unsigned)h0_ | ((unsigned)h1_ << 16);
            hw.y = (unsigned)h2_ | ((unsigned)h3_ << 16);
            lw.x = (unsigned)l0_ | ((unsigned)l1_ << 16);
            lw.y = (unsigned)l2_ | ((unsigned)l3_ << 16);
            *(uint2*)&As_hi[r][c4 * 4] = hw;
            *(uint2*)&As_lo[r][c4 * 4] = lw;
        }
        // stage B: bf16 copy (W'' is [n'][k], k contiguous)
        #pragma unroll
        for (int i = 0; i < 4; ++i) {
            int q = i * 256 + tid;            // 0..1023 : 128 rows x 8 chunks
            int n = q >> 3, c16 = q & 7;
            size_t goff = (size_t)(n0 + n) * IDIM + k0 + c16 * 8;
            *(uint4*)&Bs_hi[n][c16 * 8] = *(const uint4*)(wih_hi + goff);
            *(uint4*)&Bs_lo[n][c16 * 8] = *(const uint4*)(wih_lo + goff);
        }
        __syncthreads();

        #pragma unroll
        for (int ks = 0; ks < 2; ++ks) {
            bf16x8 ah[4], al[4], bh[4], bl[4];
            int col = ks * 32 + lc * 8;
            #pragma unroll
            for (int mb = 0; mb < 4; ++mb) {
                int row = mq + mb * 16 + lr;
                ah[mb] = *(const bf16x8*)&As_hi[row][col];
                al[mb] = *(const bf16x8*)&As_lo[row][col];
            }
            #pragma unroll
            for (int nb = 0; nb < 4; ++nb) {
                int row = nq + nb * 16 + lr;
                bh[nb] = *(const bf16x8*)&Bs_hi[row][col];
                bl[nb] = *(const bf16x8*)&Bs_lo[row][col];
            }
            #pragma unroll
            for (int mb = 0; mb < 4; ++mb)
                #pragma unroll
                for (int nb = 0; nb < 4; ++nb) {
                    acc[mb][nb] = __builtin_amdgcn_mfma_f32_16x16x32_bf16(ah[mb], bh[nb], acc[mb][nb], 0, 0, 0);
                    acc[mb][nb] = __builtin_amdgcn_mfma_f32_16x16x32_bf16(ah[mb], bl[nb], acc[mb][nb], 0, 0, 0);
                    acc[mb][nb] = __builtin_amdgcn_mfma_f32_16x16x32_bf16(al[mb], bh[nb], acc[mb][nb], 0, 0, 0);
                }
        }
        __syncthreads();
    }

    // epilogue: + bias, store f32
    #pragma unroll
    for (int mb = 0; mb < 4; ++mb) {
        #pragma unroll
        for (int nb = 0; nb < 4; ++nb) {
            int col = n0 + nq + nb * 16 + lr;
            float bias = bc[col];
            #pragma unroll
            for (int r = 0; r < 4; ++r) {
                int row = m0 + mq + mb * 16 + lc * 4 + r;
                xg[(size_t)row * G4 + col] = acc[mb][nb][r] + bias;
            }
        }
    }
}

// ---------------------------------------------------------------------------
// One LSTM time step per kernel launch. The launch boundary is the grid
// barrier: stream-ordered kernels see each other's writes (HW-maintained
// coherence), so h_pk uses plain loads/stores — no atomics, no fences, no
// spinning. 64 WGs x 256 thr; WG g owns gate cols [g*32,g*32+32); wave w
// owns K-quarter [w*128,(w+1)*128). c and running h-sum live in global fp32.
// ---------------------------------------------------------------------------
__global__ __launch_bounds__(256) void lstm_step(
        const unsigned short* __restrict__ whh_hi, const unsigned short* __restrict__ whh_lo,
        const float* __restrict__ xg,
        const float* __restrict__ mask_h, const float* __restrict__ mask_c,
        unsigned int* __restrict__ h_pk,
        float* __restrict__ c_state, float* __restrict__ h_sum,
        int t) {
    __shared__ float red[4][64][32];        // 32 KB: per-wave K-partials

    int g = blockIdx.x, tid = threadIdx.x;
    int w = tid >> 6, l = tid & 63;
    int lr = l & 15, lc = l >> 4;
    int cur = (t & 1) * (BATCH * HDIM);
    int nxt = ((t + 1) & 1) * (BATCH * HDIM);

    // B fragments (Whh'' slice) — L2-resident after step 0 (same 64 KB/WG)
    bf16x8 bh[2][4], bl[2][4];
    #pragma unroll
    for (int nb = 0; nb < 2; ++nb)
        #pragma unroll
        for (int ks = 0; ks < 4; ++ks) {
            int n = g * 32 + nb * 16 + lr;
            int k = w * 128 + ks * 32 + lc * 8;
            bh[nb][ks] = *(const bf16x8*)(whh_hi + (size_t)n * HDIM + k);
            bl[nb][ks] = *(const bf16x8*)(whh_lo + (size_t)n * HDIM + k);
        }

    f32x4 acc[4][2] = {};
    #pragma unroll
    for (int ks = 0; ks < 4; ++ks) {
        int k = w * 128 + ks * 32 + lc * 8;
        #pragma unroll
        for (int mb = 0; mb < 4; ++mb) {
            int row = mb * 16 + lr;
            const unsigned long long* pq = (const unsigned long long*)(h_pk + cur + row * HDIM + k);
            unsigned long long q0 = pq[0], q1 = pq[1], q2 = pq[2], q3 = pq[3];
            union { unsigned int d[4]; bf16x8 v; } ahu, alu;
            {
                unsigned p0 = (unsigned)q0, p1 = (unsigned)(q0 >> 32);
                ahu.d[0] = __builtin_amdgcn_perm(p1, p0, 0x05040100u);
                alu.d[0] = __builtin_amdgcn_perm(p1, p0, 0x07060302u);
            }
            {
                unsigned p0 = (unsigned)q1, p1 = (unsigned)(q1 >> 32);
                ahu.d[1] = __builtin_amdgcn_perm(p1, p0, 0x05040100u);
                alu.d[1] = __builtin_amdgcn_perm(p1, p0, 0x07060302u);
            }
            {
                unsigned p0 = (unsigned)q2, p1 = (unsigned)(q2 >> 32);
                ahu.d[2] = __builtin_amdgcn_perm(p1, p0, 0x05040100u);
                alu.d[2] = __builtin_amdgcn_perm(p1, p0, 0x07060302u);
            }
            {
                unsigned p0 = (unsigned)q3, p1 = (unsigned)(q3 >> 32);
                ahu.d[3] = __builtin_amdgcn_perm(p1, p0, 0x05040100u);
                alu.d[3] = __builtin_amdgcn_perm(p1, p0, 0x07060302u);
            }
            bf16x8 ah = ahu.v, al = alu.v;
            #pragma unroll
            for (int nb = 0; nb < 2; ++nb) {
                acc[mb][nb] = __builtin_amdgcn_mfma_f32_16x16x32_bf16(ah, bh[nb][ks], acc[mb][nb], 0, 0, 0);
                acc[mb][nb] = __builtin_amdgcn_mfma_f32_16x16x32_bf16(ah, bl[nb][ks], acc[mb][nb], 0, 0, 0);
                acc[mb][nb] = __builtin_amdgcn_mfma_f32_16x16x32_bf16(al, bh[nb][ks], acc[mb][nb], 0, 0, 0);
            }
        }
    }
    #pragma unroll
    for (int mb = 0; mb < 4; ++mb)
        #pragma unroll
        for (int nb = 0; nb < 2; ++nb)
            #pragma unroll
            for (int r = 0; r < 4; ++r)
                red[w][mb * 16 + lc * 4 + r][nb * 16 + lr] = acc[mb][nb][r];
    __syncthreads();

    // cell phase: 2 cells per thread
    int b0_ = tid >> 3, jl0 = tid & 7, jg0 = g * 8 + jl0;
    int b1_ = (tid + 256) >> 3, jl1 = tid & 7, jg1 = g * 8 + jl1;
    #pragma unroll
    for (int e = 0; e < 2; ++e) {
        int b  = e ? b1_ : b0_;
        int jl = e ? jl1 : jl0;
        int jg = e ? jg1 : jg0;
        int nb4 = jl * 4;
        float gi = red[0][b][nb4 + 0] + red[1][b][nb4 + 0] + red[2][b][nb4 + 0] + red[3][b][nb4 + 0];
        float gf = red[0][b][nb4 + 1] + red[1][b][nb4 + 1] + red[2][b][nb4 + 1] + red[3][b][nb4 + 1];
        float gg = red[0][b][nb4 + 2] + red[1][b][nb4 + 2] + red[2][b][nb4 + 2] + red[3][b][nb4 + 2];
        float go = red[0][b][nb4 + 3] + red[1][b][nb4 + 3] + red[2][b][nb4 + 3] + red[3][b][nb4 + 3];
        const float4 xgv = *(const float4*)(xg + (size_t)(t * BATCH + b) * G4 + g * 32 + nb4);
        gi += xgv.x; gf += xgv.y; gg += xgv.z; go += xgv.w;
        size_t sidx = (size_t)b * HDIM + jg;
        size_t midx = (size_t)(t * BATCH + b) * HDIM + jg;
        float c_reg = c_state[sidx];
        float i_s = sigm_fast(gi);
        float f_s = sigm_fast(gf);
        float o_s = sigm_fast(go);
        float c_new = f_s * c_reg + i_s * tanh_fast(gg);
        float h_new = o_s * tanh_fast(c_new);
        h_new *= mask_h[midx];
        c_new *= mask_c[midx];
        c_state[sidx] = c_new;
        h_sum[sidx] += h_new;
        unsigned short hh = f2bf(h_new);
        unsigned short hl = f2bf(h_new - bf2f(hh));
        h_pk[nxt + sidx] = (unsigned)hh | ((unsigned)hl << 16);
    }
}

// ---------------------------------------------------------------------------
// Projection: WG g handles batch b = g -> out[g*11 + cl]
// ---------------------------------------------------------------------------
__global__ __launch_bounds__(256) void proj_kernel(
        const float* __restrict__ h_sum,
        const float* __restrict__ W_out, const float* __restrict__ b_out,
        float* __restrict__ out) {
    __shared__ float rbuf[NCLS * 256];
    int g = blockIdx.x, tid = threadIdx.x;
    float part[NCLS];
    #pragma unroll
    for (int cl = 0; cl < NCLS; ++cl) part[cl] = 0.f;
    for (int j = tid; j < HDIM; j += 256) {
        float hv = h_sum[g * HDIM + j] * (1.f / T_STEPS);
        #pragma unroll
        for (int cl = 0; cl < NCLS; ++cl)
            part[cl] += hv * W_out[cl * HDIM + j];
    }
    #pragma unroll
    for (int cl = 0; cl < NCLS; ++cl) rbuf[cl * 256 + tid] = part[cl];
    __syncthreads();
    if (tid < NCLS) {
        float s = b_out[tid];
        for (int i = 0; i < 256; ++i) s += rbuf[tid * 256 + i];
        out[g * NCLS + tid] = s;
    }
}

// ---------------------------------------------------------------------------
extern "C" void kernel_launch(void* const* d_in, const int* in_sizes, int n_in,
                              void* d_out, int out_size, void* d_ws, size_t ws_size,
                              hipStream_t stream) {
    const float* x      = (const float*)d_in[0];
    const float* h0     = (const float*)d_in[1];
    const float* c0     = (const float*)d_in[2];
    const float* W_ih   = (const float*)d_in[3];
    const float* W_hh   = (const float*)d_in[4];
    const float* b_ih   = (const float*)d_in[5];
    const float* b_hh   = (const float*)d_in[6];
    const float* W_out  = (const float*)d_in[7];
    const float* b_out  = (const float*)d_in[8];
    const float* mask_h = (const float*)d_in[9];
    const float* mask_c = (const float*)d_in[10];
    float* out = (float*)d_out;

    char* ws = (char*)d_ws;
    float*          xg      = (float*)(ws + 0);                  // 67,108,864 B
    unsigned short* wih_hi  = (unsigned short*)(ws + 67108864);  // 8,388,608
    unsigned short* wih_lo  = (unsigned short*)(ws + 75497472);  // 8,388,608
    unsigned short* whh_hi  = (unsigned short*)(ws + 83886080);  // 2,097,152
    unsigned short* whh_lo  = (unsigned short*)(ws + 85983232);  // 2,097,152
    float*          bc      = (float*)(ws + 88080384);           // 8,192
    unsigned int*   h_pk    = (unsigned int*)(ws + 88088576);    // 262,144 (2 bufs)
    float*          c_state = (float*)(ws + 88350720);           // 131,072
    float*          h_sum   = (float*)(ws + 88481792);           // 131,072

    prep_kernel<<<8192, 256, 0, stream>>>(W_ih, W_hh, b_ih, b_hh, h0, c0,
                                          wih_hi, wih_lo, whh_hi, whh_lo, bc,
                                          h_pk, c_state, h_sum);
    gemm_xg<<<1024, 256, 0, stream>>>(x, wih_hi, wih_lo, bc, xg);

    for (int t = 0; t < T_STEPS; ++t)
        lstm_step<<<64, 256, 0, stream>>>(whh_hi, whh_lo, xg, mask_h, mask_c,
                                          h_pk, c_state, h_sum, t);

    proj_kernel<<<64, 256, 0, stream>>>(h_sum, W_out, b_out, out);
}